// Round 5
// baseline (3418.258 us; speedup 1.0000x reference)
//
#include <hip/hip_runtime.h>
#include <math.h>

#define N   2048
#define NT  256

// stable logaddexp (fallback kernel only)
__device__ __forceinline__ float lae(float a, float b) {
    float m  = fmaxf(a, b);
    float mn = fminf(a, b);
    return m + log1pf(expf(mn - m));
}

// exact integer block weight: sum_{j=h}^{e} (N-j)
__device__ __forceinline__ int wsum(int h, int e) {
    return (((N - h) + (N - e)) * (e - h + 1)) >> 1;
}

// ============================================================================
// Kernel 1: per-row bitonic sort, packed u64 (desc-sortable key | index).
// Stable: ties broken by ascending original index == jnp.argsort(-theta).
// Writes E = exp(theta_sorted) row-major + u16 original indices.
// ============================================================================
__global__ void __launch_bounds__(NT)
sort_kernel(const float* __restrict__ x1, const float* __restrict__ x2,
            int nrows, float* __restrict__ ss, unsigned short* __restrict__ sidx)
{
    __shared__ unsigned long long s_kv[N];   // 16 KB

    const int rid = blockIdx.x;
    const int tid = threadIdx.x;
    const float* __restrict__ x = (rid < nrows) ? x1 : x2;
    const size_t base = (size_t)(rid < nrows ? rid : rid - nrows) * N;

    for (int j = tid; j < N; j += NT) {
        float th = x[base + j] * 10.0f;              // theta = x / EPS
        unsigned int u = __float_as_uint(th);
        unsigned int a = (u & 0x80000000u) ? ~u : (u ^ 0x80000000u); // asc-sortable
        s_kv[j] = ((unsigned long long)(~a) << 32) | (unsigned int)j; // desc key
    }
    __syncthreads();

    for (int k = 2; k <= N; k <<= 1) {
        for (int jj = k >> 1; jj > 0; jj >>= 1) {
            for (int i = tid; i < N; i += NT) {
                int l = i ^ jj;
                if (l > i) {
                    unsigned long long a = s_kv[i], b = s_kv[l];
                    unsigned long long mn = (a < b) ? a : b;
                    unsigned long long mx = (a < b) ? b : a;
                    bool up = ((i & k) == 0);
                    s_kv[i] = up ? mn : mx;          // ascending by kv = descending theta
                    s_kv[l] = up ? mx : mn;
                }
            }
            __syncthreads();
        }
    }

    float* __restrict__ so = ss + (size_t)rid * N;
    unsigned short* __restrict__ io = sidx + (size_t)rid * N;
    for (int j = tid; j < N; j += NT) {
        unsigned long long kv = s_kv[j];
        unsigned int a = ~(unsigned int)(kv >> 32);
        unsigned int u = (a & 0x80000000u) ? (a ^ 0x80000000u) : ~a;
        so[j] = __expf(__uint_as_float(u));          // store E = exp(theta)
        io[j] = (unsigned short)(kv & 0xFFFFu);
    }
}

// ============================================================================
// Tiled 64x64 transpose: src[R][C] -> dst[C][R]. Coalesced both directions.
// grid = (C/64, R/64), 256 threads.
// ============================================================================
__global__ void __launch_bounds__(256)
transpose_kernel(const float* __restrict__ src, float* __restrict__ dst,
                 int R, int C)
{
    __shared__ float tile[64][65];
    const int bx = blockIdx.x;            // tile col in src
    const int by = blockIdx.y;            // tile row in src
    const int tx = threadIdx.x & 63;
    const int ty = threadIdx.x >> 6;      // 0..3
    #pragma unroll
    for (int yy = 0; yy < 64; yy += 4)
        tile[yy + ty][tx] = src[(size_t)(by * 64 + yy + ty) * C + bx * 64 + tx];
    __syncthreads();
    #pragma unroll
    for (int yy = 0; yy < 64; yy += 4)
        dst[(size_t)(bx * 64 + yy + ty) * R + by * 64 + tx] = tile[tx][yy + ty];
}

// ============================================================================
// Kernel 2: lane-per-row exp-domain stack PAV, COLUMN-MAJOR data.
// ssT[j][rid]: wave-uniform j -> perfectly coalesced 256B loads.
// 16-deep register prefetch ring hides HBM latency on the uniform stream.
// Stack in global [depth][rid] (coalesced across lanes), entry = fp32 Y with
// 11-bit block head round-packed into low mantissa bits; top-of-stack kept
// exact in registers. Expansion = forward uniform-j sweep writing r in place.
// ============================================================================
__global__ void __launch_bounds__(64)
pav_lane_kernel(float* __restrict__ ssT, unsigned int* __restrict__ stk, int total)
{
    const int rid = blockIdx.x * 64 + threadIdx.x;

    float buf[16];
    #pragma unroll
    for (int d = 0; d < 16; ++d) buf[d] = ssT[(size_t)d * total + rid];

    int   sp  = 0;
    int   t0h = 0,   t1h = 0;
    float t0Y = 0.f, t1Y = 0.f;   // top / below-top register cache (top exact)

    for (int g = 0; g < N / 16; ++g) {
        #pragma unroll
        for (int q = 0; q < 16; ++q) {
            const int j = g * 16 + q;
            float E = buf[q];
            if (g + 1 < N / 16) buf[q] = ssT[(size_t)(j + 16) * total + rid];

            float cY  = E;
            int   ch  = j;
            float cWf = (float)(N - j);
            while (sp > 0) {
                float tWf = (float)wsum(t0h, ch - 1);
                if (t0Y * cWf > cY * tWf) break;       // strictly decreasing: stop
                cY += t0Y;                              // pool top into current
                ch  = t0h;
                cWf = (float)wsum(ch, j);
                --sp;
                t0Y = t1Y; t0h = t1h;
                if (sp >= 2) {                          // refill below-top
                    unsigned u = stk[(size_t)(sp - 2) * total + rid];
                    t1h = (int)(u & 0x7FFu);
                    t1Y = __uint_as_float(u & 0xFFFFF800u);
                }
            }
            // push (round-to-nearest mantissa pack, head in low 11 bits)
            unsigned pu = ((__float_as_uint(cY) + 0x400u) & 0xFFFFF800u) | (unsigned)ch;
            stk[(size_t)sp * total + rid] = pu;
            ++sp;
            t1Y = t0Y; t1h = t0h;
            t0Y = cY;  t0h = ch;                        // keep top exact
        }
    }

    // ---- expansion: forward sweep, uniform j, coalesced in-place r write ----
    {
        unsigned u0 = stk[rid];                         // block 0 (head 0)
        float Y  = __uint_as_float(u0 & 0xFFFFF800u);
        int   b  = 0;
        int   nh = (sp > 1) ? (int)(stk[(size_t)1 * total + rid] & 0x7FFu) : N;
        float c  = (float)wsum(0, nh - 1) / Y;

        #pragma unroll
        for (int d = 0; d < 16; ++d) buf[d] = ssT[(size_t)d * total + rid];
        for (int g = 0; g < N / 16; ++g) {
            #pragma unroll
            for (int q = 0; q < 16; ++q) {
                const int j = g * 16 + q;
                float E = buf[q];
                if (g + 1 < N / 16) buf[q] = ssT[(size_t)(j + 16) * total + rid];
                if (j == nh) {                          // advance to next block
                    ++b;
                    unsigned ub = stk[(size_t)b * total + rid];
                    float Yb = __uint_as_float(ub & 0xFFFFF800u);
                    nh = (b + 1 < sp) ? (int)(stk[(size_t)(b + 1) * total + rid] & 0x7FFu) : N;
                    c  = (float)wsum(j, nh - 1) / Yb;
                }
                ssT[(size_t)j * total + rid] = E * c;   // r_sorted = E * W / Y
            }
        }
    }
}

// ============================================================================
// Kernel 3: fused scatter + correlation. r1 scattered to original order via
// LDS; r2 gathered against it. S/Q sums are permutation-invariant.
// ============================================================================
__global__ void __launch_bounds__(NT)
corr_fused_kernel(const float* __restrict__ rsorted,
                  const unsigned short* __restrict__ sidx,
                  int nrows, float* __restrict__ out)
{
    __shared__ float s_r1[N];
    __shared__ float s_red[NT / 64][5];
    const int p   = blockIdx.x;
    const int tid = threadIdx.x;
    const float*          r1 = rsorted + (size_t)p * N;
    const float*          r2 = rsorted + (size_t)(p + nrows) * N;
    const unsigned short* i1 = sidx + (size_t)p * N;
    const unsigned short* i2 = sidx + (size_t)(p + nrows) * N;

    float S1 = 0.f, Q1 = 0.f, S2 = 0.f, Q2 = 0.f, P = 0.f;
    for (int j = tid; j < N; j += NT) {
        float a = r1[j];
        s_r1[i1[j]] = a;
        S1 += a; Q1 += a * a;
    }
    __syncthreads();
    for (int j = tid; j < N; j += NT) {
        float b = r2[j];
        float a = s_r1[i2[j]];
        S2 += b; Q2 += b * b; P += a * b;
    }

    #pragma unroll
    for (int off = 32; off > 0; off >>= 1) {
        S1 += __shfl_down(S1, off);
        Q1 += __shfl_down(Q1, off);
        S2 += __shfl_down(S2, off);
        Q2 += __shfl_down(Q2, off);
        P  += __shfl_down(P,  off);
    }
    const int wid = tid >> 6, lane = tid & 63;
    if (lane == 0) {
        s_red[wid][0] = S1; s_red[wid][1] = Q1; s_red[wid][2] = S2;
        s_red[wid][3] = Q2; s_red[wid][4] = P;
    }
    __syncthreads();
    if (tid == 0) {
        for (int w = 1; w < NT / 64; ++w) {
            S1 += s_red[w][0]; Q1 += s_red[w][1]; S2 += s_red[w][2];
            Q2 += s_red[w][3]; P  += s_red[w][4];
        }
        const float inv_n = 1.0f / (float)N;
        float num = P  - S1 * S2 * inv_n;
        float d1  = Q1 - S1 * S1 * inv_n;
        float d2  = Q2 - S2 * S2 * inv_n;
        out[p] = 1.0f - num / sqrtf(d1 * d2);
    }
}

// ============================================================================
// Fallback: validated monolithic kernel (used only if ws too small)
// ============================================================================
__global__ void __launch_bounds__(NT)
soft_spearman_mono(const float* __restrict__ x1,
                   const float* __restrict__ x2,
                   float* __restrict__ out)
{
    __shared__ float s_key[N];
    __shared__ int   s_idx[N];
    __shared__ float s_r1[N];
    __shared__ float s_ly[N];
    __shared__ float s_lw[N];
    __shared__ float s_sol[N];
    __shared__ int   s_tgt[N];
    __shared__ int   s_nb;
    __shared__ float s_red[NT / 64][5];

    const int row = blockIdx.x;
    const int tid = threadIdx.x;

    float S1 = 0.f, Q1 = 0.f, S2 = 0.f, Q2 = 0.f, P = 0.f;

    for (int phase = 0; phase < 2; ++phase) {
        const float* __restrict__ x = (phase == 0) ? x1 : x2;
        const size_t base = (size_t)row * N;

        for (int j = tid; j < N; j += NT) {
            s_key[j] = x[base + j] * 10.0f;
            s_idx[j] = j;
        }
        __syncthreads();

        for (int k = 2; k <= N; k <<= 1) {
            for (int jj = k >> 1; jj > 0; jj >>= 1) {
                for (int i = tid; i < N; i += NT) {
                    int l = i ^ jj;
                    if (l > i) {
                        float ki = s_key[i], kl = s_key[l];
                        bool sw = ((i & k) == 0) ? (ki < kl) : (ki > kl);
                        if (sw) {
                            s_key[i] = kl; s_key[l] = ki;
                            int t = s_idx[i]; s_idx[i] = s_idx[l]; s_idx[l] = t;
                        }
                    }
                }
                __syncthreads();
            }
        }

        for (int j = tid; j < N; j += NT) {
            float y = s_key[j];
            float w = logf((float)(N - j));
            s_ly[j]  = y;
            s_lw[j]  = w;
            s_sol[j] = y - w;
            s_tgt[j] = j;
        }
        __syncthreads();

        if (tid == 0) {
            int i = 0;
            while (i < N) {
                int k = s_tgt[i] + 1;
                if (k >= N) break;
                if (s_sol[i] > s_sol[k]) { i = k; continue; }
                float sol_prev = s_sol[i];
                for (;;) {
                    float ly = lae(s_ly[i], s_ly[k]);
                    float lw = lae(s_lw[i], s_lw[k]);
                    s_ly[i] = ly; s_lw[i] = lw; s_sol[i] = ly - lw;
                    int kn = s_tgt[k] + 1;
                    if (kn >= N || sol_prev > s_sol[kn]) {
                        s_tgt[i] = kn - 1;
                        s_tgt[kn - 1] = i;
                        if (i > 0) i = s_tgt[i - 1];
                        break;
                    }
                    k = kn;
                }
            }
            int nb = 0, h = 0;
            while (h < N) {
                int e  = s_tgt[h];
                int hh = h;
                h = e + 1;
                s_tgt[nb++] = hh;
            }
            s_nb = nb;
        }
        __syncthreads();

        const int nb = s_nb;
        for (int j = tid; j < N; j += NT) {
            int lo = 0, hi = nb - 1;
            while (lo < hi) {
                int mid = (lo + hi + 1) >> 1;
                if (s_tgt[mid] <= j) lo = mid; else hi = mid - 1;
            }
            float r = expf(s_key[j] - s_sol[s_tgt[lo]]);
            int   v = s_idx[j];
            if (phase == 0) {
                s_r1[v] = r;
                S1 += r; Q1 += r * r;
            } else {
                float a = s_r1[v];
                S2 += r; Q2 += r * r; P += a * r;
            }
        }
        __syncthreads();
    }

    #pragma unroll
    for (int off = 32; off > 0; off >>= 1) {
        S1 += __shfl_down(S1, off);
        Q1 += __shfl_down(Q1, off);
        S2 += __shfl_down(S2, off);
        Q2 += __shfl_down(Q2, off);
        P  += __shfl_down(P,  off);
    }
    const int wid = tid >> 6, lane = tid & 63;
    if (lane == 0) {
        s_red[wid][0] = S1; s_red[wid][1] = Q1; s_red[wid][2] = S2;
        s_red[wid][3] = Q2; s_red[wid][4] = P;
    }
    __syncthreads();
    if (tid == 0) {
        for (int w = 1; w < NT / 64; ++w) {
            S1 += s_red[w][0]; Q1 += s_red[w][1]; S2 += s_red[w][2];
            Q2 += s_red[w][3]; P  += s_red[w][4];
        }
        const float inv_n = 1.0f / (float)N;
        float num = P  - S1 * S2 * inv_n;
        float d1  = Q1 - S1 * S1 * inv_n;
        float d2  = Q2 - S2 * S2 * inv_n;
        out[row] = 1.0f - num / sqrtf(d1 * d2);
    }
}

extern "C" void kernel_launch(void* const* d_in, const int* in_sizes, int n_in,
                              void* d_out, int out_size, void* d_ws, size_t ws_size,
                              hipStream_t stream) {
    const float* x1 = (const float*)d_in[0];
    const float* x2 = (const float*)d_in[1];
    float* out = (float*)d_out;
    const int nrows = in_sizes[0] / N;        // 4096
    const int total = 2 * nrows;              // 8192 (row,phase) pairs

    // Buffer A: E row-major -> (aliased) PAV stack -> r row-major   (64 MB)
    // Buffer B: E col-major -> r col-major (in place)               (64 MB)
    // Buffer C: sorted indices u16                                  (32 MB)
    const size_t SZ_A = (size_t)total * N * sizeof(float);
    const size_t SZ_B = (size_t)total * N * sizeof(float);
    const size_t SZ_C = (size_t)total * N * sizeof(unsigned short);
    const size_t need = SZ_A + SZ_B + SZ_C;   // 160 MB (same as validated R3/R4)

    if (ws_size >= need) {
        float*          A    = (float*)d_ws;
        float*          B    = (float*)((char*)d_ws + SZ_A);
        unsigned short* sidx = (unsigned short*)((char*)d_ws + SZ_A + SZ_B);
        unsigned int*   stk  = (unsigned int*)A;          // aliases A (E rm dead)

        sort_kernel<<<total, NT, 0, stream>>>(x1, x2, nrows, A, sidx);
        {   // A[total][N] -> B[N][total]
            dim3 g(N / 64, total / 64);
            transpose_kernel<<<g, 256, 0, stream>>>(A, B, total, N);
        }
        pav_lane_kernel<<<total / 64, 64, 0, stream>>>(B, stk, total);
        {   // B[N][total] (now r) -> A[total][N]
            dim3 g(total / 64, N / 64);
            transpose_kernel<<<g, 256, 0, stream>>>(B, A, N, total);
        }
        corr_fused_kernel<<<nrows, NT, 0, stream>>>(A, sidx, nrows, out);
    } else {
        soft_spearman_mono<<<nrows, NT, 0, stream>>>(x1, x2, out);
    }
}

// Round 6
// 768.920 us; speedup vs baseline: 4.4455x; 4.4455x over previous
//
#include <hip/hip_runtime.h>
#include <math.h>

#define N   2048
#define NT  256

// stable logaddexp (fallback kernel only)
__device__ __forceinline__ float lae(float a, float b) {
    float m  = fmaxf(a, b);
    float mn = fminf(a, b);
    return m + log1pf(expf(mn - m));
}

// exact integer block weight: sum_{j=h}^{e} (N-j)  (< 2^22, exact in fp32)
__device__ __forceinline__ int wsum(int h, int e) {
    return (((N - h) + (N - e)) * (e - h + 1)) >> 1;
}

// padded LDS index for element j: lane-row j>>5 padded to 33 floats
__device__ __forceinline__ int eidx(int j) { return (j >> 5) * 33 + (j & 31); }

// ============================================================================
// Kernel 1: per-row bitonic sort, packed u64 (desc-sortable key | index).
// Stable: ties broken by ascending original index == jnp.argsort(-theta).
// Writes E = exp(theta_sorted) row-major + u16 original indices.
// ============================================================================
__global__ void __launch_bounds__(NT)
sort_kernel(const float* __restrict__ x1, const float* __restrict__ x2,
            int nrows, float* __restrict__ ss, unsigned short* __restrict__ sidx)
{
    __shared__ unsigned long long s_kv[N];   // 16 KB

    const int rid = blockIdx.x;
    const int tid = threadIdx.x;
    const float* __restrict__ x = (rid < nrows) ? x1 : x2;
    const size_t base = (size_t)(rid < nrows ? rid : rid - nrows) * N;

    for (int j = tid; j < N; j += NT) {
        float th = x[base + j] * 10.0f;              // theta = x / EPS
        unsigned int u = __float_as_uint(th);
        unsigned int a = (u & 0x80000000u) ? ~u : (u ^ 0x80000000u); // asc-sortable
        s_kv[j] = ((unsigned long long)(~a) << 32) | (unsigned int)j; // desc key
    }
    __syncthreads();

    for (int k = 2; k <= N; k <<= 1) {
        for (int jj = k >> 1; jj > 0; jj >>= 1) {
            for (int i = tid; i < N; i += NT) {
                int l = i ^ jj;
                if (l > i) {
                    unsigned long long a = s_kv[i], b = s_kv[l];
                    unsigned long long mn = (a < b) ? a : b;
                    unsigned long long mx = (a < b) ? b : a;
                    bool up = ((i & k) == 0);
                    s_kv[i] = up ? mn : mx;          // ascending by kv = descending theta
                    s_kv[l] = up ? mx : mn;
                }
            }
            __syncthreads();
        }
    }

    float* __restrict__ so = ss + (size_t)rid * N;
    unsigned short* __restrict__ io = sidx + (size_t)rid * N;
    for (int j = tid; j < N; j += NT) {
        unsigned long long kv = s_kv[j];
        unsigned int a = ~(unsigned int)(kv >> 32);
        unsigned int u = (a & 0x80000000u) ? (a ^ 0x80000000u) : ~a;
        so[j] = __expf(__uint_as_float(u));          // store E = exp(theta)
        io[j] = (unsigned short)(kv & 0xFFFFu);
    }
}

// next block head after (lane, d) within lanes [.., bEnd); bEnd*32 if none
__device__ __forceinline__ int next_head(const unsigned short* stH,
                                         const unsigned char* sBeg,
                                         const unsigned char* sEnd,
                                         int lane, int d, int bEnd)
{
    if (d + 1 < (int)sEnd[lane]) return stH[(d + 1) * 64 + lane];
    for (int l = lane + 1; l < bEnd; ++l)
        if (sBeg[l] != sEnd[l]) return stH[(int)sBeg[l] * 64 + l];
    return bEnd << 5;
}

// ============================================================================
// Kernel 2: wave-parallel PAV. One wave per row.
// Phase 1: each lane runs exp-domain stack PAV on its 32-element segment
//          (stack in LDS [depth][lane], top-2 cached in registers).
// Phase 2: 6 merge rounds; each merge resolves only the boundary cascade
//          (stops at first non-pooling block — partitions strictly decrease).
// Phase 3: per-lane block expansion r = E * W / Y in LDS, coalesced writeback
//          in place over the E buffer.
// ============================================================================
__global__ void __launch_bounds__(64)
pav_wave_kernel(float* __restrict__ ss)
{
    __shared__ float          sE[64 * 33];       // 8448 B padded E -> r
    __shared__ float          stY[32 * 64];      // 8192 B  [d][lane]
    __shared__ unsigned short stH[32 * 64];      // 4096 B  [d][lane]
    __shared__ unsigned char  sBeg[64], sEnd[64];

    const int rid = blockIdx.x;
    const int t   = threadIdx.x;
    float* __restrict__ row = ss + (size_t)rid * N;

    for (int j = t; j < N; j += 64) sE[eidx(j)] = row[j];
    __syncthreads();

    // ---- phase 1: per-lane stack PAV on segment [32t, 32t+32) ----
    {
        int   sp = 0;
        float t0Y = 0.f, t1Y = 0.f;
        int   t0h = 0,   t1h = 0;
        const int base = t << 5;
        for (int k = 0; k < 32; ++k) {
            const int j = base + k;
            float cY = sE[t * 33 + k];
            int   ch = j;
            while (sp > 0) {
                float cW = (float)wsum(ch, j);
                float tW = (float)wsum(t0h, ch - 1);
                if (t0Y * cW > cY * tW) break;     // strictly decreasing: stop
                cY += t0Y; ch = t0h;               // pool top into current
                --sp;
                t0Y = t1Y; t0h = t1h;
                if (sp > 1) { t1Y = stY[(sp - 2) * 64 + t]; t1h = stH[(sp - 2) * 64 + t]; }
            }
            stY[sp * 64 + t] = cY;
            stH[sp * 64 + t] = (unsigned short)ch;
            t1Y = t0Y; t1h = t0h;
            t0Y = cY;  t0h = ch;
            ++sp;
        }
        sBeg[t] = 0; sEnd[t] = (unsigned char)sp;
    }
    __syncthreads();

    // ---- phase 2: merge tree (6 levels) ----
    for (int lev = 0; lev < 6; ++lev) {
        const int g = 1 << lev;
        if ((t & (2 * g - 1)) == 0) {
            const int a = t, mid = t + g, b = t + 2 * g;
            int l0 = mid - 1;                       // last nonempty lane of G0
            while (l0 >= a && sBeg[l0] == sEnd[l0]) --l0;
            int l1 = mid;                           // first nonempty lane of G1
            while (l1 < b && sBeg[l1] == sEnd[l1]) ++l1;
            if (l0 >= a && l1 < b) {
                int   d0 = (int)sEnd[l0] - 1;
                float tY = stY[d0 * 64 + l0];
                int   th = stH[d0 * 64 + l0];
                int   te = (mid << 5) - 1;          // G0's last block end (tiles range)
                int   d1 = (int)sBeg[l1];
                float cY = stY[d1 * 64 + l1];
                int   ch = stH[d1 * 64 + l1];
                int   ce = next_head(stH, sBeg, sEnd, l1, d1, b) - 1;
                if (!(tY * (float)wsum(ch, ce) > cY * (float)wsum(th, te))) {
                    sBeg[l1] = (unsigned char)(d1 + 1);   // consume G1 front
                    for (;;) {
                        if (l0 >= a &&
                            !(tY * (float)wsum(ch, ce) > cY * (float)wsum(th, te))) {
                            // pool left: cur absorbs G0 top [th, ch-1]
                            cY += tY;
                            ch  = th;
                            sEnd[l0] = (unsigned char)((int)sEnd[l0] - 1);
                            if (sBeg[l0] == sEnd[l0]) {
                                do { --l0; } while (l0 >= a && sBeg[l0] == sEnd[l0]);
                            }
                            if (l0 >= a) {
                                int dd = (int)sEnd[l0] - 1;
                                tY = stY[dd * 64 + l0];
                                te = th - 1;        // new top's end = absorbed head - 1
                                th = stH[dd * 64 + l0];
                            }
                            continue;
                        }
                        // try pool right: next G1 block
                        while (l1 < b && sBeg[l1] == sEnd[l1]) ++l1;
                        if (l1 < b) {
                            int   dn = (int)sBeg[l1];
                            float nY = stY[dn * 64 + l1];
                            int   nh = stH[dn * 64 + l1];
                            int   ne = next_head(stH, sBeg, sEnd, l1, dn, b) - 1;
                            if (!(cY * (float)wsum(nh, ne) > nY * (float)wsum(ch, ce))) {
                                cY += nY; ce = ne;          // absorb next
                                sBeg[l1] = (unsigned char)(dn + 1);
                                continue;
                            }
                        }
                        break;
                    }
                    // push cur back at its head's lane
                    int lh = ch >> 5;
                    if (ch >= (mid << 5)) {          // head in G1 -> front push
                        int nb = (int)sBeg[lh] - 1;
                        sBeg[lh] = (unsigned char)nb;
                        stY[nb * 64 + lh] = cY;
                        stH[nb * 64 + lh] = (unsigned short)ch;
                    } else {                          // head in G0 -> tail push
                        int nb2 = (int)sEnd[lh];
                        stY[nb2 * 64 + lh] = cY;
                        stH[nb2 * 64 + lh] = (unsigned short)ch;
                        sEnd[lh] = (unsigned char)(nb2 + 1);
                    }
                }
            }
        }
        __syncthreads();
    }

    // ---- phase 3: expansion r = E * W / Y, per-lane over its blocks ----
    for (int d = (int)sBeg[t]; d < (int)sEnd[t]; ++d) {
        int   h = stH[d * 64 + t];
        int   e = next_head(stH, sBeg, sEnd, t, d, 64) - 1;
        float c = (float)wsum(h, e) / stY[d * 64 + t];
        for (int j = h; j <= e; ++j) sE[eidx(j)] *= c;
    }
    __syncthreads();
    for (int j = t; j < N; j += 64) row[j] = sE[eidx(j)];
}

// ============================================================================
// Kernel 3: fused scatter + correlation. r1 scattered to original order via
// LDS; r2 gathered against it. S/Q sums are permutation-invariant.
// ============================================================================
__global__ void __launch_bounds__(NT)
corr_fused_kernel(const float* __restrict__ rsorted,
                  const unsigned short* __restrict__ sidx,
                  int nrows, float* __restrict__ out)
{
    __shared__ float s_r1[N];
    __shared__ float s_red[NT / 64][5];
    const int p   = blockIdx.x;
    const int tid = threadIdx.x;
    const float*          r1 = rsorted + (size_t)p * N;
    const float*          r2 = rsorted + (size_t)(p + nrows) * N;
    const unsigned short* i1 = sidx + (size_t)p * N;
    const unsigned short* i2 = sidx + (size_t)(p + nrows) * N;

    float S1 = 0.f, Q1 = 0.f, S2 = 0.f, Q2 = 0.f, P = 0.f;
    for (int j = tid; j < N; j += NT) {
        float a = r1[j];
        s_r1[i1[j]] = a;
        S1 += a; Q1 += a * a;
    }
    __syncthreads();
    for (int j = tid; j < N; j += NT) {
        float b = r2[j];
        float a = s_r1[i2[j]];
        S2 += b; Q2 += b * b; P += a * b;
    }

    #pragma unroll
    for (int off = 32; off > 0; off >>= 1) {
        S1 += __shfl_down(S1, off);
        Q1 += __shfl_down(Q1, off);
        S2 += __shfl_down(S2, off);
        Q2 += __shfl_down(Q2, off);
        P  += __shfl_down(P,  off);
    }
    const int wid = tid >> 6, lane = tid & 63;
    if (lane == 0) {
        s_red[wid][0] = S1; s_red[wid][1] = Q1; s_red[wid][2] = S2;
        s_red[wid][3] = Q2; s_red[wid][4] = P;
    }
    __syncthreads();
    if (tid == 0) {
        for (int w = 1; w < NT / 64; ++w) {
            S1 += s_red[w][0]; Q1 += s_red[w][1]; S2 += s_red[w][2];
            Q2 += s_red[w][3]; P  += s_red[w][4];
        }
        const float inv_n = 1.0f / (float)N;
        float num = P  - S1 * S2 * inv_n;
        float d1  = Q1 - S1 * S1 * inv_n;
        float d2  = Q2 - S2 * S2 * inv_n;
        out[p] = 1.0f - num / sqrtf(d1 * d2);
    }
}

// ============================================================================
// Fallback: validated monolithic kernel (used only if ws too small)
// ============================================================================
__global__ void __launch_bounds__(NT)
soft_spearman_mono(const float* __restrict__ x1,
                   const float* __restrict__ x2,
                   float* __restrict__ out)
{
    __shared__ float s_key[N];
    __shared__ int   s_idx[N];
    __shared__ float s_r1[N];
    __shared__ float s_ly[N];
    __shared__ float s_lw[N];
    __shared__ float s_sol[N];
    __shared__ int   s_tgt[N];
    __shared__ int   s_nb;
    __shared__ float s_red[NT / 64][5];

    const int row = blockIdx.x;
    const int tid = threadIdx.x;

    float S1 = 0.f, Q1 = 0.f, S2 = 0.f, Q2 = 0.f, P = 0.f;

    for (int phase = 0; phase < 2; ++phase) {
        const float* __restrict__ x = (phase == 0) ? x1 : x2;
        const size_t base = (size_t)row * N;

        for (int j = tid; j < N; j += NT) {
            s_key[j] = x[base + j] * 10.0f;
            s_idx[j] = j;
        }
        __syncthreads();

        for (int k = 2; k <= N; k <<= 1) {
            for (int jj = k >> 1; jj > 0; jj >>= 1) {
                for (int i = tid; i < N; i += NT) {
                    int l = i ^ jj;
                    if (l > i) {
                        float ki = s_key[i], kl = s_key[l];
                        bool sw = ((i & k) == 0) ? (ki < kl) : (ki > kl);
                        if (sw) {
                            s_key[i] = kl; s_key[l] = ki;
                            int t = s_idx[i]; s_idx[i] = s_idx[l]; s_idx[l] = t;
                        }
                    }
                }
                __syncthreads();
            }
        }

        for (int j = tid; j < N; j += NT) {
            float y = s_key[j];
            float w = logf((float)(N - j));
            s_ly[j]  = y;
            s_lw[j]  = w;
            s_sol[j] = y - w;
            s_tgt[j] = j;
        }
        __syncthreads();

        if (tid == 0) {
            int i = 0;
            while (i < N) {
                int k = s_tgt[i] + 1;
                if (k >= N) break;
                if (s_sol[i] > s_sol[k]) { i = k; continue; }
                float sol_prev = s_sol[i];
                for (;;) {
                    float ly = lae(s_ly[i], s_ly[k]);
                    float lw = lae(s_lw[i], s_lw[k]);
                    s_ly[i] = ly; s_lw[i] = lw; s_sol[i] = ly - lw;
                    int kn = s_tgt[k] + 1;
                    if (kn >= N || sol_prev > s_sol[kn]) {
                        s_tgt[i] = kn - 1;
                        s_tgt[kn - 1] = i;
                        if (i > 0) i = s_tgt[i - 1];
                        break;
                    }
                    k = kn;
                }
            }
            int nb = 0, h = 0;
            while (h < N) {
                int e  = s_tgt[h];
                int hh = h;
                h = e + 1;
                s_tgt[nb++] = hh;
            }
            s_nb = nb;
        }
        __syncthreads();

        const int nb = s_nb;
        for (int j = tid; j < N; j += NT) {
            int lo = 0, hi = nb - 1;
            while (lo < hi) {
                int mid = (lo + hi + 1) >> 1;
                if (s_tgt[mid] <= j) lo = mid; else hi = mid - 1;
            }
            float r = expf(s_key[j] - s_sol[s_tgt[lo]]);
            int   v = s_idx[j];
            if (phase == 0) {
                s_r1[v] = r;
                S1 += r; Q1 += r * r;
            } else {
                float a = s_r1[v];
                S2 += r; Q2 += r * r; P += a * r;
            }
        }
        __syncthreads();
    }

    #pragma unroll
    for (int off = 32; off > 0; off >>= 1) {
        S1 += __shfl_down(S1, off);
        Q1 += __shfl_down(Q1, off);
        S2 += __shfl_down(S2, off);
        Q2 += __shfl_down(Q2, off);
        P  += __shfl_down(P,  off);
    }
    const int wid = tid >> 6, lane = tid & 63;
    if (lane == 0) {
        s_red[wid][0] = S1; s_red[wid][1] = Q1; s_red[wid][2] = S2;
        s_red[wid][3] = Q2; s_red[wid][4] = P;
    }
    __syncthreads();
    if (tid == 0) {
        for (int w = 1; w < NT / 64; ++w) {
            S1 += s_red[w][0]; Q1 += s_red[w][1]; S2 += s_red[w][2];
            Q2 += s_red[w][3]; P  += s_red[w][4];
        }
        const float inv_n = 1.0f / (float)N;
        float num = P  - S1 * S2 * inv_n;
        float d1  = Q1 - S1 * S1 * inv_n;
        float d2  = Q2 - S2 * S2 * inv_n;
        out[row] = 1.0f - num / sqrtf(d1 * d2);
    }
}

extern "C" void kernel_launch(void* const* d_in, const int* in_sizes, int n_in,
                              void* d_out, int out_size, void* d_ws, size_t ws_size,
                              hipStream_t stream) {
    const float* x1 = (const float*)d_in[0];
    const float* x2 = (const float*)d_in[1];
    float* out = (float*)d_out;
    const int nrows = in_sizes[0] / N;        // 4096
    const int total = 2 * nrows;              // 8192 (row,phase) pairs

    // Buffer A: E row-major -> r row-major (in place)   (64 MB)
    // Buffer C: sorted indices u16                      (32 MB)
    const size_t SZ_A = (size_t)total * N * sizeof(float);
    const size_t SZ_C = (size_t)total * N * sizeof(unsigned short);
    const size_t need = SZ_A + SZ_C;          // 96 MB

    if (ws_size >= need) {
        float*          A    = (float*)d_ws;
        unsigned short* sidx = (unsigned short*)((char*)d_ws + SZ_A);

        sort_kernel<<<total, NT, 0, stream>>>(x1, x2, nrows, A, sidx);
        pav_wave_kernel<<<total, 64, 0, stream>>>(A);
        corr_fused_kernel<<<nrows, NT, 0, stream>>>(A, sidx, nrows, out);
    } else {
        soft_spearman_mono<<<nrows, NT, 0, stream>>>(x1, x2, out);
    }
}

// Round 7
// 475.354 us; speedup vs baseline: 7.1910x; 1.6176x over previous
//
#include <hip/hip_runtime.h>
#include <math.h>

#define N   2048
#define NT  256
#define V   8

// stable logaddexp (fallback kernel only)
__device__ __forceinline__ float lae(float a, float b) {
    float m  = fmaxf(a, b);
    float mn = fminf(a, b);
    return m + log1pf(expf(mn - m));
}

// exact integer block weight: sum_{j=h}^{e} (N-j)  (< 2^22, exact in fp32)
__device__ __forceinline__ int wsum(int h, int e) {
    return (((N - h) + (N - e)) * (e - h + 1)) >> 1;
}

// padded LDS index for element j: lane-row j>>5 padded to 33 floats
__device__ __forceinline__ int eidx(int j) { return (j >> 5) * 33 + (j & 31); }

// ---- register bitonic helpers -------------------------------------------
__device__ __forceinline__ void ceu(unsigned long long &a, unsigned long long &b, bool up) {
    unsigned long long mn = (a < b) ? a : b;
    unsigned long long mx = (a < b) ? b : a;
    a = up ? mn : mx;
    b = up ? mx : mn;
}

__device__ __forceinline__ void merge8(unsigned long long* r, bool up) {
    ceu(r[0], r[4], up); ceu(r[1], r[5], up); ceu(r[2], r[6], up); ceu(r[3], r[7], up);
    ceu(r[0], r[2], up); ceu(r[1], r[3], up); ceu(r[4], r[6], up); ceu(r[5], r[7], up);
    ceu(r[0], r[1], up); ceu(r[2], r[3], up); ceu(r[4], r[5], up); ceu(r[6], r[7], up);
}

__device__ __forceinline__ void shfl_ce(unsigned long long* r, int d, bool keepMin) {
    #pragma unroll
    for (int q = 0; q < V; ++q) {
        unsigned lo = __shfl_xor((unsigned)r[q], d, 64);
        unsigned hi = __shfl_xor((unsigned)(r[q] >> 32), d, 64);
        unsigned long long p = ((unsigned long long)hi << 32) | lo;
        bool lt = r[q] < p;
        r[q] = (lt == keepMin) ? r[q] : p;   // keepMin? min : max
    }
}

// ============================================================================
// Kernel 1: registerized per-row bitonic sort, u64 kv = (desc key | index).
// V=8 elems/thread in registers; jj<=4 substages in regs, 8<=jj<=256 via
// __shfl_xor, jj in {512,1024} via LDS (3 substages, 6 barriers total).
// Stable: ties broken by ascending original index == jnp.argsort(-theta).
// Writes E = exp(theta_sorted) row-major + u16 original indices.
// ============================================================================
__global__ void __launch_bounds__(NT)
sort_kernel(const float* __restrict__ x1, const float* __restrict__ x2,
            int nrows, float* __restrict__ ss, unsigned short* __restrict__ sidx)
{
    __shared__ unsigned long long s_kv[N];   // 16 KB

    const int rid = blockIdx.x;
    const int tid = threadIdx.x;
    const float* __restrict__ x = (rid < nrows) ? x1 : x2;
    const size_t base = (size_t)(rid < nrows ? rid : rid - nrows) * N;

    // ---- load 8 elements into registers, encode sortable kv ----
    const float4* __restrict__ xv = (const float4*)(x + base + tid * V);
    float4 a0 = xv[0], a1 = xv[1];
    float th[V] = {a0.x, a0.y, a0.z, a0.w, a1.x, a1.y, a1.z, a1.w};
    unsigned long long r[V];
    #pragma unroll
    for (int q = 0; q < V; ++q) {
        float t = th[q] * 10.0f;                     // theta = x / EPS
        unsigned u = __float_as_uint(t);
        unsigned a = (u & 0x80000000u) ? ~u : (u ^ 0x80000000u);  // asc-sortable
        r[q] = ((unsigned long long)(~a) << 32) | (unsigned)(tid * V + q);
    }

    // ---- k=2, k=4 local stages (directions compile-time per q) ----
    ceu(r[0], r[1], true);  ceu(r[2], r[3], false);
    ceu(r[4], r[5], true);  ceu(r[6], r[7], false);
    ceu(r[0], r[2], true);  ceu(r[1], r[3], true);
    ceu(r[4], r[6], false); ceu(r[5], r[7], false);
    ceu(r[0], r[1], true);  ceu(r[2], r[3], true);
    ceu(r[4], r[5], false); ceu(r[6], r[7], false);
    // ---- k=8 ----
    merge8(r, (tid & 1) == 0);

    // ---- k=16 .. 2048 ----
    #pragma unroll
    for (int kk = 4; kk <= 11; ++kk) {
        const int k  = 1 << kk;
        const bool up = ((tid & (k >> 3)) == 0);
        #pragma unroll
        for (int jb = kk - 1; jb >= 3; --jb) {
            const int jj = 1 << jb;
            const int d  = jj >> 3;
            if (d >= 64) {
                // cross-wave: LDS exchange
                __syncthreads();
                #pragma unroll
                for (int q = 0; q < V; ++q) s_kv[tid * V + q] = r[q];
                __syncthreads();
                const bool keepMin = (up == ((tid & d) == 0));
                const int ptid = tid ^ d;
                #pragma unroll
                for (int q = 0; q < V; ++q) {
                    unsigned long long p = s_kv[ptid * V + q];
                    bool lt = r[q] < p;
                    r[q] = (lt == keepMin) ? r[q] : p;
                }
            } else {
                shfl_ce(r, d, up == ((tid & d) == 0));
            }
        }
        merge8(r, up);
    }

    // ---- decode + store (coalesced: thread owns 8 consecutive elements) ----
    float e[V];
    unsigned long long p0 = 0, p1 = 0;
    #pragma unroll
    for (int q = 0; q < V; ++q) {
        unsigned a = ~(unsigned)(r[q] >> 32);
        unsigned u = (a & 0x80000000u) ? (a ^ 0x80000000u) : ~a;
        e[q] = __expf(__uint_as_float(u));           // E = exp(theta)
        unsigned long long id = (unsigned short)(r[q] & 0xFFFFu);
        if (q < 4) p0 |= id << (16 * q);
        else       p1 |= id << (16 * (q - 4));
    }
    float* __restrict__ so = ss + (size_t)rid * N + tid * V;
    ((float4*)so)[0] = make_float4(e[0], e[1], e[2], e[3]);
    ((float4*)so)[1] = make_float4(e[4], e[5], e[6], e[7]);
    unsigned long long* __restrict__ io =
        (unsigned long long*)(sidx + (size_t)rid * N + tid * V);
    io[0] = p0;
    io[1] = p1;
}

// next block head after (lane, d) within lanes [.., bEnd); bEnd*32 if none
__device__ __forceinline__ int next_head(const unsigned short* stH,
                                         const unsigned char* sBeg,
                                         const unsigned char* sEnd,
                                         int lane, int d, int bEnd)
{
    if (d + 1 < (int)sEnd[lane]) return stH[(d + 1) * 64 + lane];
    for (int l = lane + 1; l < bEnd; ++l)
        if (sBeg[l] != sEnd[l]) return stH[(int)sBeg[l] * 64 + l];
    return bEnd << 5;
}

// ============================================================================
// Kernel 2: wave-parallel PAV. One wave per row. (validated R6, absmax 0.0)
// ============================================================================
__global__ void __launch_bounds__(64)
pav_wave_kernel(float* __restrict__ ss)
{
    __shared__ float          sE[64 * 33];       // 8448 B padded E -> r
    __shared__ float          stY[32 * 64];      // 8192 B  [d][lane]
    __shared__ unsigned short stH[32 * 64];      // 4096 B  [d][lane]
    __shared__ unsigned char  sBeg[64], sEnd[64];

    const int rid = blockIdx.x;
    const int t   = threadIdx.x;
    float* __restrict__ row = ss + (size_t)rid * N;

    for (int j = t; j < N; j += 64) sE[eidx(j)] = row[j];
    __syncthreads();

    // ---- phase 1: per-lane stack PAV on segment [32t, 32t+32) ----
    {
        int   sp = 0;
        float t0Y = 0.f, t1Y = 0.f;
        int   t0h = 0,   t1h = 0;
        const int base = t << 5;
        for (int k = 0; k < 32; ++k) {
            const int j = base + k;
            float cY = sE[t * 33 + k];
            int   ch = j;
            while (sp > 0) {
                float cW = (float)wsum(ch, j);
                float tW = (float)wsum(t0h, ch - 1);
                if (t0Y * cW > cY * tW) break;     // strictly decreasing: stop
                cY += t0Y; ch = t0h;               // pool top into current
                --sp;
                t0Y = t1Y; t0h = t1h;
                if (sp > 1) { t1Y = stY[(sp - 2) * 64 + t]; t1h = stH[(sp - 2) * 64 + t]; }
            }
            stY[sp * 64 + t] = cY;
            stH[sp * 64 + t] = (unsigned short)ch;
            t1Y = t0Y; t1h = t0h;
            t0Y = cY;  t0h = ch;
            ++sp;
        }
        sBeg[t] = 0; sEnd[t] = (unsigned char)sp;
    }
    __syncthreads();

    // ---- phase 2: merge tree (6 levels) ----
    for (int lev = 0; lev < 6; ++lev) {
        const int g = 1 << lev;
        if ((t & (2 * g - 1)) == 0) {
            const int a = t, mid = t + g, b = t + 2 * g;
            int l0 = mid - 1;                       // last nonempty lane of G0
            while (l0 >= a && sBeg[l0] == sEnd[l0]) --l0;
            int l1 = mid;                           // first nonempty lane of G1
            while (l1 < b && sBeg[l1] == sEnd[l1]) ++l1;
            if (l0 >= a && l1 < b) {
                int   d0 = (int)sEnd[l0] - 1;
                float tY = stY[d0 * 64 + l0];
                int   th = stH[d0 * 64 + l0];
                int   te = (mid << 5) - 1;          // G0's last block end (tiles range)
                int   d1 = (int)sBeg[l1];
                float cY = stY[d1 * 64 + l1];
                int   ch = stH[d1 * 64 + l1];
                int   ce = next_head(stH, sBeg, sEnd, l1, d1, b) - 1;
                if (!(tY * (float)wsum(ch, ce) > cY * (float)wsum(th, te))) {
                    sBeg[l1] = (unsigned char)(d1 + 1);   // consume G1 front
                    for (;;) {
                        if (l0 >= a &&
                            !(tY * (float)wsum(ch, ce) > cY * (float)wsum(th, te))) {
                            // pool left: cur absorbs G0 top [th, ch-1]
                            cY += tY;
                            ch  = th;
                            sEnd[l0] = (unsigned char)((int)sEnd[l0] - 1);
                            if (sBeg[l0] == sEnd[l0]) {
                                do { --l0; } while (l0 >= a && sBeg[l0] == sEnd[l0]);
                            }
                            if (l0 >= a) {
                                int dd = (int)sEnd[l0] - 1;
                                tY = stY[dd * 64 + l0];
                                te = th - 1;        // new top's end = absorbed head - 1
                                th = stH[dd * 64 + l0];
                            }
                            continue;
                        }
                        // try pool right: next G1 block
                        while (l1 < b && sBeg[l1] == sEnd[l1]) ++l1;
                        if (l1 < b) {
                            int   dn = (int)sBeg[l1];
                            float nY = stY[dn * 64 + l1];
                            int   nh = stH[dn * 64 + l1];
                            int   ne = next_head(stH, sBeg, sEnd, l1, dn, b) - 1;
                            if (!(cY * (float)wsum(nh, ne) > nY * (float)wsum(ch, ce))) {
                                cY += nY; ce = ne;          // absorb next
                                sBeg[l1] = (unsigned char)(dn + 1);
                                continue;
                            }
                        }
                        break;
                    }
                    // push cur back at its head's lane
                    int lh = ch >> 5;
                    if (ch >= (mid << 5)) {          // head in G1 -> front push
                        int nb = (int)sBeg[lh] - 1;
                        sBeg[lh] = (unsigned char)nb;
                        stY[nb * 64 + lh] = cY;
                        stH[nb * 64 + lh] = (unsigned short)ch;
                    } else {                          // head in G0 -> tail push
                        int nb2 = (int)sEnd[lh];
                        stY[nb2 * 64 + lh] = cY;
                        stH[nb2 * 64 + lh] = (unsigned short)ch;
                        sEnd[lh] = (unsigned char)(nb2 + 1);
                    }
                }
            }
        }
        __syncthreads();
    }

    // ---- phase 3: expansion r = E * W / Y, per-lane over its blocks ----
    for (int d = (int)sBeg[t]; d < (int)sEnd[t]; ++d) {
        int   h = stH[d * 64 + t];
        int   e = next_head(stH, sBeg, sEnd, t, d, 64) - 1;
        float c = (float)wsum(h, e) / stY[d * 64 + t];
        for (int j = h; j <= e; ++j) sE[eidx(j)] *= c;
    }
    __syncthreads();
    for (int j = t; j < N; j += 64) row[j] = sE[eidx(j)];
}

// ============================================================================
// Kernel 3: fused scatter + correlation. (validated)
// ============================================================================
__global__ void __launch_bounds__(NT)
corr_fused_kernel(const float* __restrict__ rsorted,
                  const unsigned short* __restrict__ sidx,
                  int nrows, float* __restrict__ out)
{
    __shared__ float s_r1[N];
    __shared__ float s_red[NT / 64][5];
    const int p   = blockIdx.x;
    const int tid = threadIdx.x;
    const float*          r1 = rsorted + (size_t)p * N;
    const float*          r2 = rsorted + (size_t)(p + nrows) * N;
    const unsigned short* i1 = sidx + (size_t)p * N;
    const unsigned short* i2 = sidx + (size_t)(p + nrows) * N;

    float S1 = 0.f, Q1 = 0.f, S2 = 0.f, Q2 = 0.f, P = 0.f;
    for (int j = tid; j < N; j += NT) {
        float a = r1[j];
        s_r1[i1[j]] = a;
        S1 += a; Q1 += a * a;
    }
    __syncthreads();
    for (int j = tid; j < N; j += NT) {
        float b = r2[j];
        float a = s_r1[i2[j]];
        S2 += b; Q2 += b * b; P += a * b;
    }

    #pragma unroll
    for (int off = 32; off > 0; off >>= 1) {
        S1 += __shfl_down(S1, off);
        Q1 += __shfl_down(Q1, off);
        S2 += __shfl_down(S2, off);
        Q2 += __shfl_down(Q2, off);
        P  += __shfl_down(P,  off);
    }
    const int wid = tid >> 6, lane = tid & 63;
    if (lane == 0) {
        s_red[wid][0] = S1; s_red[wid][1] = Q1; s_red[wid][2] = S2;
        s_red[wid][3] = Q2; s_red[wid][4] = P;
    }
    __syncthreads();
    if (tid == 0) {
        for (int w = 1; w < NT / 64; ++w) {
            S1 += s_red[w][0]; Q1 += s_red[w][1]; S2 += s_red[w][2];
            Q2 += s_red[w][3]; P  += s_red[w][4];
        }
        const float inv_n = 1.0f / (float)N;
        float num = P  - S1 * S2 * inv_n;
        float d1  = Q1 - S1 * S1 * inv_n;
        float d2  = Q2 - S2 * S2 * inv_n;
        out[p] = 1.0f - num / sqrtf(d1 * d2);
    }
}

// ============================================================================
// Fallback: validated monolithic kernel (used only if ws too small)
// ============================================================================
__global__ void __launch_bounds__(NT)
soft_spearman_mono(const float* __restrict__ x1,
                   const float* __restrict__ x2,
                   float* __restrict__ out)
{
    __shared__ float s_key[N];
    __shared__ int   s_idx[N];
    __shared__ float s_r1[N];
    __shared__ float s_ly[N];
    __shared__ float s_lw[N];
    __shared__ float s_sol[N];
    __shared__ int   s_tgt[N];
    __shared__ int   s_nb;
    __shared__ float s_red[NT / 64][5];

    const int row = blockIdx.x;
    const int tid = threadIdx.x;

    float S1 = 0.f, Q1 = 0.f, S2 = 0.f, Q2 = 0.f, P = 0.f;

    for (int phase = 0; phase < 2; ++phase) {
        const float* __restrict__ x = (phase == 0) ? x1 : x2;
        const size_t base = (size_t)row * N;

        for (int j = tid; j < N; j += NT) {
            s_key[j] = x[base + j] * 10.0f;
            s_idx[j] = j;
        }
        __syncthreads();

        for (int k = 2; k <= N; k <<= 1) {
            for (int jj = k >> 1; jj > 0; jj >>= 1) {
                for (int i = tid; i < N; i += NT) {
                    int l = i ^ jj;
                    if (l > i) {
                        float ki = s_key[i], kl = s_key[l];
                        bool sw = ((i & k) == 0) ? (ki < kl) : (ki > kl);
                        if (sw) {
                            s_key[i] = kl; s_key[l] = ki;
                            int t = s_idx[i]; s_idx[i] = s_idx[l]; s_idx[l] = t;
                        }
                    }
                }
                __syncthreads();
            }
        }

        for (int j = tid; j < N; j += NT) {
            float y = s_key[j];
            float w = logf((float)(N - j));
            s_ly[j]  = y;
            s_lw[j]  = w;
            s_sol[j] = y - w;
            s_tgt[j] = j;
        }
        __syncthreads();

        if (tid == 0) {
            int i = 0;
            while (i < N) {
                int k = s_tgt[i] + 1;
                if (k >= N) break;
                if (s_sol[i] > s_sol[k]) { i = k; continue; }
                float sol_prev = s_sol[i];
                for (;;) {
                    float ly = lae(s_ly[i], s_ly[k]);
                    float lw = lae(s_lw[i], s_lw[k]);
                    s_ly[i] = ly; s_lw[i] = lw; s_sol[i] = ly - lw;
                    int kn = s_tgt[k] + 1;
                    if (kn >= N || sol_prev > s_sol[kn]) {
                        s_tgt[i] = kn - 1;
                        s_tgt[kn - 1] = i;
                        if (i > 0) i = s_tgt[i - 1];
                        break;
                    }
                    k = kn;
                }
            }
            int nb = 0, h = 0;
            while (h < N) {
                int e  = s_tgt[h];
                int hh = h;
                h = e + 1;
                s_tgt[nb++] = hh;
            }
            s_nb = nb;
        }
        __syncthreads();

        const int nb = s_nb;
        for (int j = tid; j < N; j += NT) {
            int lo = 0, hi = nb - 1;
            while (lo < hi) {
                int mid = (lo + hi + 1) >> 1;
                if (s_tgt[mid] <= j) lo = mid; else hi = mid - 1;
            }
            float r = expf(s_key[j] - s_sol[s_tgt[lo]]);
            int   v = s_idx[j];
            if (phase == 0) {
                s_r1[v] = r;
                S1 += r; Q1 += r * r;
            } else {
                float a = s_r1[v];
                S2 += r; Q2 += r * r; P += a * r;
            }
        }
        __syncthreads();
    }

    #pragma unroll
    for (int off = 32; off > 0; off >>= 1) {
        S1 += __shfl_down(S1, off);
        Q1 += __shfl_down(Q1, off);
        S2 += __shfl_down(S2, off);
        Q2 += __shfl_down(Q2, off);
        P  += __shfl_down(P,  off);
    }
    const int wid = tid >> 6, lane = tid & 63;
    if (lane == 0) {
        s_red[wid][0] = S1; s_red[wid][1] = Q1; s_red[wid][2] = S2;
        s_red[wid][3] = Q2; s_red[wid][4] = P;
    }
    __syncthreads();
    if (tid == 0) {
        for (int w = 1; w < NT / 64; ++w) {
            S1 += s_red[w][0]; Q1 += s_red[w][1]; S2 += s_red[w][2];
            Q2 += s_red[w][3]; P  += s_red[w][4];
        }
        const float inv_n = 1.0f / (float)N;
        float num = P  - S1 * S2 * inv_n;
        float d1  = Q1 - S1 * S1 * inv_n;
        float d2  = Q2 - S2 * S2 * inv_n;
        out[row] = 1.0f - num / sqrtf(d1 * d2);
    }
}

extern "C" void kernel_launch(void* const* d_in, const int* in_sizes, int n_in,
                              void* d_out, int out_size, void* d_ws, size_t ws_size,
                              hipStream_t stream) {
    const float* x1 = (const float*)d_in[0];
    const float* x2 = (const float*)d_in[1];
    float* out = (float*)d_out;
    const int nrows = in_sizes[0] / N;        // 4096
    const int total = 2 * nrows;              // 8192 (row,phase) pairs

    // Buffer A: E row-major -> r row-major (in place)   (64 MB)
    // Buffer C: sorted indices u16                      (32 MB)
    const size_t SZ_A = (size_t)total * N * sizeof(float);
    const size_t SZ_C = (size_t)total * N * sizeof(unsigned short);
    const size_t need = SZ_A + SZ_C;          // 96 MB

    if (ws_size >= need) {
        float*          A    = (float*)d_ws;
        unsigned short* sidx = (unsigned short*)((char*)d_ws + SZ_A);

        sort_kernel<<<total, NT, 0, stream>>>(x1, x2, nrows, A, sidx);
        pav_wave_kernel<<<total, 64, 0, stream>>>(A);
        corr_fused_kernel<<<nrows, NT, 0, stream>>>(A, sidx, nrows, out);
    } else {
        soft_spearman_mono<<<nrows, NT, 0, stream>>>(x1, x2, out);
    }
}